// Round 11
// baseline (3795.778 us; speedup 1.0000x reference)
//
#include <hip/hip_runtime.h>

// Furthest Point Sampling, B=8, C=3, N=65536, NUM_POINTS=1024.
//
// R11 = R8's minimal IC exchange + WINNER COORDS CARRIED IN THE RECORD.
//
// Evidence: R3/R8/R9/R10 invariant at ~1.65-1.8ms; FETCH_SIZE 3.4MB == 3 x
// 128B HBM lines per batch-iteration == exactly the xb/yb/zb[winner] loads.
// A fresh random index each iteration = ~900cy HBM miss ON THE SERIAL CHAIN.
// Fix: publish {key, x|tag, y|tag, z|tag} (32B) per block; the poll itself
// delivers the winner's coordinates. (R4 tried payloads and regressed, but its
// causes -- parity-line ping-pong and 4x wave-granular publish -- are fixed
// here: fresh tagged regions, block-level publish, single poller wave.)
//
//  - 16 blocks x 256 threads per batch (128 blocks; blockIdx&7 = batch).
//  - Each block's 4096 points register-resident (16 pts/thread).
//  - Per iteration (ONE barrier): scan + per-thread argmax (carrying coords) ->
//    DPP wave max; wave-winner thread stashes coords in s_wc[wave]; barrier ->
//    wave 0: DPP block max over 4 wave keys; winning wave found by ballot
//    (keys are UNIQUE: distinct idx per thread) -> lane 0 publishes the 32B
//    record (4 relaxed agent-scope u64 stores; every word tagged) -> all 64
//    lanes poll the 64-word region (one dwordx2 round per attempt) until every
//    tag matches -> DPP max over slot-keys (other words masked to 0) -> the
//    winning slot's lanes drop x,y,z into s_q; lane 0 records s_hist and
//    RELEASE-stores the parity mailbox; waves 1-3 acquire-spin on the mailbox
//    and read coords from s_q. Winner coords never touch global memory.
//  - Regions reused modulo 16, tag-validated (word low 16 bits == it): block
//    skew < 2 iterations << 16; 0xAA poison = tag 0xAAAA never matches
//    it < 1024 -> NO memset, no extra dispatch, nothing else in the launch.
//
// Key packing (idx < 65536): dist_bits(32) | (0xFFFF - idx)(16) | it(16).
// Max key = max dist, tie -> smaller index == jnp.argmax first-occurrence
// (dist >= 0 -> float bits monotone; same tag on all keys of an iteration).
// Distance math: __fmul_rn/__fadd_rn (no FMA contraction) to bit-match numpy.

namespace {

constexpr int kB = 8;
constexpr int kN = 65536;
constexpr int kNP = 1024;
constexpr int kPB = 16;                      // blocks (slices) per batch
constexpr int kThreads = 256;
constexpr int kPPT = kN / (kPB * kThreads);  // 16 points per thread
constexpr int kGrp = kPPT / 4;               // 4 float4 groups
constexpr int kWaves = kThreads / 64;        // 4
constexpr int kRgn = 16;                     // region reuse depth (skew < 2)
constexpr int kRec = 4;                      // u64 words per record
constexpr int kWords = kPB * kRec;           // 64 words per batch-iteration

__device__ __forceinline__ unsigned long long u64max(unsigned long long a,
                                                     unsigned long long b) {
  return a > b ? a : b;
}

template <int CTRL>
__device__ __forceinline__ unsigned long long dpp_u64_zero(unsigned long long v) {
  const unsigned lo =
      (unsigned)__builtin_amdgcn_update_dpp(0, (int)(unsigned)v, CTRL, 0xf, 0xf, false);
  const unsigned hi =
      (unsigned)__builtin_amdgcn_update_dpp(0, (int)(unsigned)(v >> 32), CTRL, 0xf, 0xf, false);
  return ((unsigned long long)hi << 32) | lo;
}

// 64-lane max via DPP (keys > 0 -> old=0 is an identity), broadcast lane 63.
__device__ __forceinline__ unsigned long long wave_max_u64(unsigned long long v) {
  v = u64max(v, dpp_u64_zero<0x111>(v));  // row_shr:1
  v = u64max(v, dpp_u64_zero<0x112>(v));  // row_shr:2
  v = u64max(v, dpp_u64_zero<0x114>(v));  // row_shr:4
  v = u64max(v, dpp_u64_zero<0x118>(v));  // row_shr:8
  v = u64max(v, dpp_u64_zero<0x142>(v));  // row_bcast:15
  v = u64max(v, dpp_u64_zero<0x143>(v));  // row_bcast:31
  const unsigned lo = (unsigned)__builtin_amdgcn_readlane((int)(unsigned)v, 63);
  const unsigned hi = (unsigned)__builtin_amdgcn_readlane((int)(unsigned)(v >> 32), 63);
  return ((unsigned long long)hi << 32) | lo;
}

__device__ __forceinline__ unsigned long long shfl_u64(unsigned long long v, int src) {
  return (unsigned long long)__shfl((long long)v, src, 64);
}

__global__ __launch_bounds__(kThreads) void fps_kernel(const float* __restrict__ pts,
                                                       float* __restrict__ out,
                                                       unsigned long long* __restrict__ slots) {
  const int batch = blockIdx.x & 7;
  const int slice = blockIdx.x >> 3;  // 0..15
  const int tid = threadIdx.x;
  const int lane = tid & 63;
  const int wave = tid >> 6;

  const float* __restrict__ xb = pts + (size_t)batch * 3 * kN;
  const float* __restrict__ yb = xb + kN;
  const float* __restrict__ zb = xb + 2 * kN;

  __shared__ unsigned long long s_wkey[kWaves];
  __shared__ float s_wc[kWaves][3];  // per-wave winner coords
  __shared__ float s_q[3];           // global winner coords (this iteration)
  __shared__ unsigned s_win[2];      // parity mailbox: (wi << 16) | it
  __shared__ int s_hist[kNP];

  if (tid == 0) {
    s_win[0] = 0xFFFFFFFFu;  // tag 0xFFFF never matches it < 1024
    s_win[1] = 0xFFFFFFFFu;
  }

  // Register-resident coords: block owns [slice*4096, slice*4096+4096).
  const int sbase = slice * (kThreads * kPPT);
  const int base0 = sbase + tid * 4;
  float px[kPPT], py[kPPT], pz[kPPT], dist[kPPT];
#pragma unroll
  for (int g = 0; g < kGrp; ++g) {
    const int base = base0 + g * (kThreads * 4);
    const float4 vx = *reinterpret_cast<const float4*>(xb + base);
    const float4 vy = *reinterpret_cast<const float4*>(yb + base);
    const float4 vz = *reinterpret_cast<const float4*>(zb + base);
    px[g * 4 + 0] = vx.x; px[g * 4 + 1] = vx.y; px[g * 4 + 2] = vx.z; px[g * 4 + 3] = vx.w;
    py[g * 4 + 0] = vy.x; py[g * 4 + 1] = vy.y; py[g * 4 + 2] = vy.z; py[g * 4 + 3] = vy.w;
    pz[g * 4 + 0] = vz.x; pz[g * 4 + 1] = vz.y; pz[g * 4 + 2] = vz.z; pz[g * 4 + 3] = vz.w;
  }
#pragma unroll
  for (int k = 0; k < kPPT; ++k) dist[k] = 1e10f;

  // Seed: index 0 (uniform broadcast load, once).
  float qx = xb[0], qy = yb[0], qz = zb[0];

  unsigned long long* const sb = slots + (size_t)batch * kRgn * kWords;

  for (int it = 1; it < kNP; ++it) {
    const unsigned tag = (unsigned)it;

    // --- update dists + per-thread argmax carrying coords (strict '>') ---
    float bd = -1.0f, bx = 0.f, by = 0.f, bz = 0.f;
    int bi = 0;
#pragma unroll
    for (int g = 0; g < kGrp; ++g) {
#pragma unroll
      for (int j = 0; j < 4; ++j) {
        const int k = g * 4 + j;
        const float dx = px[k] - qx;
        const float dy = py[k] - qy;
        const float dz = pz[k] - qz;
        const float ss =
            __fadd_rn(__fadd_rn(__fmul_rn(dx, dx), __fmul_rn(dy, dy)), __fmul_rn(dz, dz));
        const float nd = fminf(dist[k], ss);
        dist[k] = nd;
        if (nd > bd) {
          bd = nd;
          bi = base0 + g * (kThreads * 4) + j;
          bx = px[k]; by = py[k]; bz = pz[k];
        }
      }
    }

    // key: dist(32) | (0xFFFF - idx)(16) | it(16). Unique per thread (idx).
    const unsigned long long mykey = ((unsigned long long)__float_as_uint(bd) << 32) |
                                     ((unsigned long long)(0xFFFFu - (unsigned)bi) << 16) |
                                     (unsigned long long)tag;

    // --- DPP wave max; the (unique) wave-winner thread stashes its coords ---
    const unsigned long long wk = wave_max_u64(mykey);
    if (mykey == wk) {
      s_wc[wave][0] = bx;
      s_wc[wave][1] = by;
      s_wc[wave][2] = bz;
    }
    if (lane == 0) s_wkey[wave] = wk;
    __syncthreads();  // the only barrier in the iteration

    if (wave == 0) {
      // --- block max over 4 wave keys (DPP on replicated lanes) ---
      const unsigned long long lk = s_wkey[lane & (kWaves - 1)];
      const unsigned long long bk = wave_max_u64(lk);
      // Winning wave is unique (keys unique) -> ballot + ffs.
      const unsigned long long m = __ballot(lane < kWaves && lk == bk);
      const int winwave = (int)(__ffsll((long long)m) - 1);

      unsigned long long* const rgn = sb + (size_t)(it & (kRgn - 1)) * kWords;
      if (lane == 0) {
        const float wx = s_wc[winwave][0];
        const float wy = s_wc[winwave][1];
        const float wz = s_wc[winwave][2];
        unsigned long long* const my = rgn + slice * kRec;
        __hip_atomic_store(my + 0, bk, __ATOMIC_RELAXED, __HIP_MEMORY_SCOPE_AGENT);
        __hip_atomic_store(my + 1, ((unsigned long long)__float_as_uint(wx) << 32) | tag,
                           __ATOMIC_RELAXED, __HIP_MEMORY_SCOPE_AGENT);
        __hip_atomic_store(my + 2, ((unsigned long long)__float_as_uint(wy) << 32) | tag,
                           __ATOMIC_RELAXED, __HIP_MEMORY_SCOPE_AGENT);
        __hip_atomic_store(my + 3, ((unsigned long long)__float_as_uint(wz) << 32) | tag,
                           __ATOMIC_RELAXED, __HIP_MEMORY_SCOPE_AGENT);
      }

      // --- poll: 64 words == 64 lanes, one dwordx2 round per attempt ---
      unsigned long long w;
      for (;;) {
        w = __hip_atomic_load(rgn + lane, __ATOMIC_RELAXED, __HIP_MEMORY_SCOPE_AGENT);
        if (__all((unsigned)(w & 0xFFFFull) == tag)) break;
      }

      // --- DPP max over slot-keys (lanes with word!=0 masked to 0) ---
      const unsigned long long kw = ((lane & 3) == 0) ? w : 0ull;
      const unsigned long long mx = wave_max_u64(kw);
      // Winning slot's lanes (slot key == mx, words 1..3) drop coords into s_q.
      const unsigned long long skey = shfl_u64(w, lane & ~3);
      const int wrd = lane & 3;
      if (skey == mx && wrd != 0) {
        s_q[wrd - 1] = __uint_as_float((unsigned)(w >> 32));
      }
      const int wi = (int)(0xFFFFu - ((unsigned)(mx >> 16) & 0xFFFFu));
      if (lane == 0) {
        s_hist[it] = wi;
        // RELEASE: orders the s_q writes (earlier DS instructions of this
        // wave) before the mailbox flag for the acquiring waves.
        __hip_atomic_store(&s_win[it & 1], ((unsigned)wi << 16) | tag, __ATOMIC_RELEASE,
                           __HIP_MEMORY_SCOPE_WORKGROUP);
      }
      // Wave 0 reads its own s_q (DS ops of one wave complete in order).
      qx = s_q[0];
      qy = s_q[1];
      qz = s_q[2];
    } else {
      // --- waves 1-3: acquire-spin on the mailbox, coords from LDS ---
      unsigned v;
      do {
        v = __hip_atomic_load(&s_win[it & 1], __ATOMIC_ACQUIRE, __HIP_MEMORY_SCOPE_WORKGROUP);
      } while ((v & 0xFFFFu) != tag);
      qx = s_q[0];
      qy = s_q[1];
      qz = s_q[2];
    }
  }

  __syncthreads();  // s_hist complete and visible block-wide

  // --- gather: out[b][c][j] = points[b][c][idx_j]; slice-0 block per batch ---
  if (slice == 0) {
    float* __restrict__ ob = out + (size_t)batch * 3 * kNP;
    for (int j = tid; j < kNP; j += kThreads) {
      const int id = (j == 0) ? 0 : s_hist[j];
      ob[j] = xb[id];
      ob[kNP + j] = yb[id];
      ob[2 * kNP + j] = zb[id];
    }
  }
}

}  // namespace

extern "C" void kernel_launch(void* const* d_in, const int* in_sizes, int n_in,
                              void* d_out, int out_size, void* d_ws, size_t ws_size,
                              hipStream_t stream) {
  (void)in_sizes;
  (void)n_in;
  (void)out_size;
  (void)ws_size;
  const float* pts = (const float*)d_in[0];
  float* out = (float*)d_out;
  // 8 batches x 16 regions x 64 u64 = 64 KB of d_ws. Tag-validated (0xAA
  // poison -> tag 0xAAAA never equals it < 1024) => NO memset; region reuse
  // depth 16 >> max block skew (< 2 iterations).
  unsigned long long* slots = (unsigned long long*)d_ws;
  fps_kernel<<<dim3(kB * kPB), dim3(kThreads), 0, stream>>>(pts, out, slots);
}

// Round 12
// 1729.240 us; speedup vs baseline: 2.1951x; 2.1951x over previous
//
#include <hip/hip_runtime.h>

// Furthest Point Sampling, B=8, C=3, N=65536, NUM_POINTS=1024.
//
// R12 = R8/R9 protocol (PROVEN invariants: one 8B publish per block, ONE 128B
// polled line per batch-iteration, single poller wave, tagged depth-16 regions,
// no memset) + two serial-chain cuts:
//   (1) PIPELINED POLL: keep 2 poll loads in flight (issue next before testing
//       current) so detection quantization ~RTT/2 instead of ~RTT.
//   (2) CANDIDATE-COORDS PREFETCH: poller lanes 0-15, when their slot first
//       turns valid, issue loads of that candidate's x,y,z (scattered clean
//       lines; no interference with the hot slot line). When the winner is
//       known, its coords are (usually) already in registers -> shuffle from
//       the winning lane; fan out to waves 1-3 via LDS s_q under the release
//       mailbox. Kills the ~600cy random-line coords load on the chain.
//
// Law learned R4/R7/R11: multi-word records / multi-line polls blow up IC
// write traffic 4x and double iteration time. Never again.
//
// Key packing (idx < 65536): dist_bits(32) | (0xFFFF - idx)(16) | it(16).
// Max key = max dist, tie -> smaller index == jnp.argmax first-occurrence
// (dist >= 0 -> float bits monotone; same tag on all keys of an iteration).
// Winning slice = wi >> 12 (block owns [slice*4096, slice*4096+4096)).
// Distance math: __fmul_rn/__fadd_rn (no FMA contraction) to bit-match numpy.

namespace {

constexpr int kB = 8;
constexpr int kN = 65536;
constexpr int kNP = 1024;
constexpr int kPB = 16;                      // blocks (slices) per batch
constexpr int kThreads = 256;
constexpr int kPPT = kN / (kPB * kThreads);  // 16 points per thread
constexpr int kGrp = kPPT / 4;               // 4 float4 groups
constexpr int kWaves = kThreads / 64;        // 4
constexpr int kRgn = 16;                     // region reuse depth (skew < 2)

__device__ __forceinline__ unsigned long long u64max(unsigned long long a,
                                                     unsigned long long b) {
  return a > b ? a : b;
}

template <int CTRL>
__device__ __forceinline__ unsigned long long dpp_u64_zero(unsigned long long v) {
  const unsigned lo =
      (unsigned)__builtin_amdgcn_update_dpp(0, (int)(unsigned)v, CTRL, 0xf, 0xf, false);
  const unsigned hi =
      (unsigned)__builtin_amdgcn_update_dpp(0, (int)(unsigned)(v >> 32), CTRL, 0xf, 0xf, false);
  return ((unsigned long long)hi << 32) | lo;
}

// 64-lane max via DPP (keys > 0 -> old=0 is an identity), broadcast lane 63.
__device__ __forceinline__ unsigned long long wave_max_u64(unsigned long long v) {
  v = u64max(v, dpp_u64_zero<0x111>(v));  // row_shr:1
  v = u64max(v, dpp_u64_zero<0x112>(v));  // row_shr:2
  v = u64max(v, dpp_u64_zero<0x114>(v));  // row_shr:4
  v = u64max(v, dpp_u64_zero<0x118>(v));  // row_shr:8
  v = u64max(v, dpp_u64_zero<0x142>(v));  // row_bcast:15
  v = u64max(v, dpp_u64_zero<0x143>(v));  // row_bcast:31
  const unsigned lo = (unsigned)__builtin_amdgcn_readlane((int)(unsigned)v, 63);
  const unsigned hi = (unsigned)__builtin_amdgcn_readlane((int)(unsigned)(v >> 32), 63);
  return ((unsigned long long)hi << 32) | lo;
}

__global__ __launch_bounds__(kThreads) void fps_kernel(const float* __restrict__ pts,
                                                       float* __restrict__ out,
                                                       unsigned long long* __restrict__ slots) {
  const int batch = blockIdx.x & 7;
  const int slice = blockIdx.x >> 3;  // 0..15
  const int tid = threadIdx.x;
  const int lane = tid & 63;
  const int wave = tid >> 6;

  const float* __restrict__ xb = pts + (size_t)batch * 3 * kN;
  const float* __restrict__ yb = xb + kN;
  const float* __restrict__ zb = xb + 2 * kN;

  __shared__ unsigned long long s_wkey[kWaves];
  __shared__ float s_q[3];       // winner coords (this iteration)
  __shared__ unsigned s_win[2];  // parity mailbox: (wi << 16) | it
  __shared__ int s_hist[kNP];

  if (tid == 0) {
    s_win[0] = 0xFFFFFFFFu;  // tag 0xFFFF never matches it < 1024
    s_win[1] = 0xFFFFFFFFu;
  }

  // Register-resident coords: block owns [slice*4096, slice*4096+4096).
  const int sbase = slice * (kThreads * kPPT);
  const int base0 = sbase + tid * 4;
  float px[kPPT], py[kPPT], pz[kPPT], dist[kPPT];
#pragma unroll
  for (int g = 0; g < kGrp; ++g) {
    const int base = base0 + g * (kThreads * 4);
    const float4 vx = *reinterpret_cast<const float4*>(xb + base);
    const float4 vy = *reinterpret_cast<const float4*>(yb + base);
    const float4 vz = *reinterpret_cast<const float4*>(zb + base);
    px[g * 4 + 0] = vx.x; px[g * 4 + 1] = vx.y; px[g * 4 + 2] = vx.z; px[g * 4 + 3] = vx.w;
    py[g * 4 + 0] = vy.x; py[g * 4 + 1] = vy.y; py[g * 4 + 2] = vy.z; py[g * 4 + 3] = vy.w;
    pz[g * 4 + 0] = vz.x; pz[g * 4 + 1] = vz.y; pz[g * 4 + 2] = vz.z; pz[g * 4 + 3] = vz.w;
  }
#pragma unroll
  for (int k = 0; k < kPPT; ++k) dist[k] = 1e10f;

  // Seed: index 0 (uniform broadcast load, once).
  float qx = xb[0], qy = yb[0], qz = zb[0];

  unsigned long long* const sb = slots + (size_t)batch * kRgn * kPB;

  for (int it = 1; it < kNP; ++it) {
    const unsigned tag = (unsigned)it;

    // --- update dists + per-thread argmax (ascending index, strict '>') ---
    float bd = -1.0f;
    int bi = 0;
#pragma unroll
    for (int g = 0; g < kGrp; ++g) {
#pragma unroll
      for (int j = 0; j < 4; ++j) {
        const int k = g * 4 + j;
        const float dx = px[k] - qx;
        const float dy = py[k] - qy;
        const float dz = pz[k] - qz;
        const float ss =
            __fadd_rn(__fadd_rn(__fmul_rn(dx, dx), __fmul_rn(dy, dy)), __fmul_rn(dz, dz));
        const float nd = fminf(dist[k], ss);
        dist[k] = nd;
        if (nd > bd) {
          bd = nd;
          bi = base0 + g * (kThreads * 4) + j;
        }
      }
    }

    // key: dist(32) | (0xFFFF - idx)(16) | it(16)  -- tag self-validates slots.
    unsigned long long key = ((unsigned long long)__float_as_uint(bd) << 32) |
                             ((unsigned long long)(0xFFFFu - (unsigned)bi) << 16) |
                             (unsigned long long)tag;

    // --- DPP wave max ---
    key = wave_max_u64(key);
    if (lane == 0) s_wkey[wave] = key;
    __syncthreads();  // the only barrier in the iteration

    if (wave == 0) {
      // --- block max over 4 wave keys (DPP on replicated lanes) ---
      unsigned long long bk = s_wkey[lane & (kWaves - 1)];
      bk = wave_max_u64(bk);

      unsigned long long* const rgn = sb + (size_t)(it & (kRgn - 1)) * kPB;
      if (lane == 0) {
        __hip_atomic_store(rgn + slice, bk, __ATOMIC_RELAXED, __HIP_MEMORY_SCOPE_AGENT);
      }

      // --- pipelined poll (2 in flight) + candidate-coords prefetch ---
      const unsigned long long* const myslot = rgn + (lane & (kPB - 1));
      float cx = 0.f, cy = 0.f, cz = 0.f;
      bool have = false;
      unsigned long long w;
      unsigned long long a =
          __hip_atomic_load(myslot, __ATOMIC_RELAXED, __HIP_MEMORY_SCOPE_AGENT);
      for (;;) {
        // Issue the next poll load BEFORE testing the current one, so the
        // compiler can wait at depth vmcnt(1) while one stays in flight.
        unsigned long long b =
            __hip_atomic_load(myslot, __ATOMIC_RELAXED, __HIP_MEMORY_SCOPE_AGENT);
        const bool va = (unsigned)(a & 0xFFFFull) == tag;
        // Prefetch this slot's candidate coords the moment it turns valid
        // (lanes 0..15 only; scattered clean lines, off the hot slot line).
        if ((lane < kPB) && va && !have) {
          const int ci = (int)(0xFFFFu - ((unsigned)(a >> 16) & 0xFFFFu));
          cx = xb[ci];
          cy = yb[ci];
          cz = zb[ci];
          have = true;
        }
        if (__all(va)) {
          w = a;
          break;
        }
        a = b;
      }

      // --- DPP max over 16 slots (4x replicated lanes) ---
      const unsigned long long mx = wave_max_u64(w);
      const int wi = (int)(0xFFFFu - ((unsigned)(mx >> 16) & 0xFFFFu));
      const int winslot = wi >> 12;  // slice that owns index wi
      // Winner coords from the prefetching lane (already in flight/registers).
      qx = __shfl(cx, winslot, 64);
      qy = __shfl(cy, winslot, 64);
      qz = __shfl(cz, winslot, 64);
      if (lane == 0) {
        s_hist[it] = wi;
        s_q[0] = qx;
        s_q[1] = qy;
        s_q[2] = qz;
        // RELEASE orders the s_q stores before the mailbox flag.
        __hip_atomic_store(&s_win[it & 1], ((unsigned)wi << 16) | tag, __ATOMIC_RELEASE,
                           __HIP_MEMORY_SCOPE_WORKGROUP);
      }
    } else {
      // --- waves 1-3: acquire-spin on the mailbox; coords from LDS ---
      unsigned v;
      do {
        v = __hip_atomic_load(&s_win[it & 1], __ATOMIC_ACQUIRE, __HIP_MEMORY_SCOPE_WORKGROUP);
      } while ((v & 0xFFFFu) != tag);
      qx = s_q[0];
      qy = s_q[1];
      qz = s_q[2];
    }
  }

  __syncthreads();  // s_hist complete and visible block-wide

  // --- gather: out[b][c][j] = points[b][c][idx_j]; slice-0 block per batch ---
  if (slice == 0) {
    float* __restrict__ ob = out + (size_t)batch * 3 * kNP;
    for (int j = tid; j < kNP; j += kThreads) {
      const int id = (j == 0) ? 0 : s_hist[j];
      ob[j] = xb[id];
      ob[kNP + j] = yb[id];
      ob[2 * kNP + j] = zb[id];
    }
  }
}

}  // namespace

extern "C" void kernel_launch(void* const* d_in, const int* in_sizes, int n_in,
                              void* d_out, int out_size, void* d_ws, size_t ws_size,
                              hipStream_t stream) {
  (void)in_sizes;
  (void)n_in;
  (void)out_size;
  (void)ws_size;
  const float* pts = (const float*)d_in[0];
  float* out = (float*)d_out;
  // 8 batches x 16 regions x 16 slots x 8B = 16 KB of d_ws. Tag-validated
  // (0xAA poison -> tag 0xAAAA never equals it < 1024) => NO memset; region
  // reuse depth 16 >> max block skew (< 2 iterations).
  unsigned long long* slots = (unsigned long long*)d_ws;
  fps_kernel<<<dim3(kB * kPB), dim3(kThreads), 0, stream>>>(pts, out, slots);
}